// Round 7
// baseline (27.218 us; speedup 1.0000x reference)
//
#include <hip/hip_runtime.h>
#include <math.h>

#define NUM_CLASSES 80
#define BB 16
#define AA 3
#define HH 85
#define WW 85
#define HW (HH*WW)
#define MM 50
#define CH (AA*(5+NUM_CLASSES))   // 255
#define TPB 512
#define BX ((HW + TPB - 1)/TPB)   // 15 hw-windows per (b,a)
#define NBA (BB*AA)               // 48 columns
#define NBLK (BX*NBA)             // 720 blocks

__device__ __forceinline__ float sigmoidf_(float x){ return 1.0f/(1.0f+expf(-x)); }
// bce(sigmoid(x),t) == softplus(x) - t*x (exact; no saturation for |x| < ~16)
__device__ __forceinline__ float softplus_(float x){
    return fmaxf(x, 0.0f) + log1pf(expf(-fabsf(x)));
}
__device__ __forceinline__ double atomicExchD(double* p, double v){
    unsigned long long old = atomicExch((unsigned long long*)p, __double_as_longlong(v));
    return __longlong_as_double(old);
}

// ws layout (128B-line separated):
//   acc_l [16 lines]  @ 0      : striped f64 loss partials (relaxed atomicAdd)
//   acc_lc[16 lines]  @ 2048   : per-batch conditional-conf partials
//   posfl [16 lines]  @ 4096   : per-batch any-positive flags
//   colcnt[48 lines]  @ 6144   : per-ba column tickets (15 blocks each)
//   cnt   [1]         @ 12288  : global ticket (48 column-winners only)
__global__ void __launch_bounds__(TPB) k_all(
        const float* __restrict__ outputs,
        const float* __restrict__ targets,
        const float* __restrict__ masked_anchors,
        const float* __restrict__ ref_anchors,
        const int* __restrict__ anchor_mask,
        char* __restrict__ wsb,
        float* __restrict__ out)
{
    double* acc_l  = (double*)(wsb);
    double* acc_lc = (double*)(wsb + 2048);
    int*    posfl  = (int*)(wsb + 4096);
    unsigned int* colcnt = (unsigned int*)(wsb + 6144);
    unsigned int* cnt    = (unsigned int*)(wsb + 12288);

    __shared__ float4 s_gbox[MM];        // (gx1, gy1, gx2, gy2)
    __shared__ float  s_ga[MM];          // garea
    __shared__ float4 s_dd[MM];          // delta (dx, dy, dw, dh)
    __shared__ float  s_scale[MM];
    __shared__ int    s_no;
    __shared__ int    s_win[TPB];
    __shared__ unsigned int s_cm[TPB][3];
    __shared__ double s_rl[8], s_rlc[8];
    __shared__ int    s_anyw[8];
    __shared__ int    s_prev;
    __shared__ double s_fa[16], s_fc[16];
    __shared__ int    s_fp[16];

    const int tid  = threadIdx.x;
    const int ba   = blockIdx.y;           // b*AA + a (column id)
    const int b    = ba / AA, a = ba % AA;
    const int base = blockIdx.x * TPB;
    const int bid  = ba * BX + blockIdx.x;

    // Clean poisoned column ticket. At check time this block hasn't incremented,
    // so live values are <= BX-1 = 14; CAS on v>=BX can never hit live state.
    if (tid == 0){
        unsigned int v = __hip_atomic_load(&colcnt[ba*32], __ATOMIC_RELAXED,
                                           __HIP_MEMORY_SCOPE_AGENT);
        if (v >= (unsigned int)BX) atomicCAS(&colcnt[ba*32], v, 0u);
    }

    s_win[tid] = -1;
    s_cm[tid][0] = 0u; s_cm[tid][1] = 0u; s_cm[tid][2] = 0u;

    // ---- phase A: per-GT metadata for batch b (threads 0..MM-1, wave 0) ----
    float g0=0.f,g1=0.f,g2=0.f,g3=0.f,g4=0.f;
    bool gflag = false;
    if (tid < MM){
        const float* g = targets + ((size_t)b*MM + tid)*5;
        g0=g[0]; g1=g[1]; g2=g[2]; g3=g[3]; g4=g[4];
        gflag = (g0+g1+g2+g3+g4) > 0.0f;
    }
    unsigned long long bal = __ballot(gflag);
    if (tid == 0) s_no = __popcll(bal);
    __syncthreads();
    const int no = s_no;

    if (tid < MM){
        float gx = g0*(float)WW, gy = g1*(float)HH, gw = g2*(float)WW, gh = g3*(float)HH;
        int cls = min(max((int)g4, 0), NUM_CLASSES-1);
        bool valid = (tid < no);
        int cx = (int)floorf(gx), cy = (int)floorf(gy);
        int cell = min(max(cy*WW + cx, 0), HW-1);
        float xg = (float)(cell % WW), yg = (float)(cell / WW);
        float gx1 = gx - gw*0.5f, gy1 = gy - gh*0.5f;
        float gx2 = gx + gw*0.5f, gy2 = gy + gh*0.5f;
        float garea = gw*gh;
        // 9-anchor argmax via cross-multiplication (first-max-wins, like jnp.argmax)
        float bai = -1.0f, bun = 1.0f; int aidx = 0;
        for (int r = 0; r < 9; ++r){
            float off = (r % 3 == 0) ? 0.5f : 0.0f;  // ref_grid.at[:, 0::3, :2].add(0.5)
            float acx = xg + off, acy = yg + off;
            float aw = ref_anchors[2*r], ah = ref_anchors[2*r+1];
            float w = fminf(acx + aw*0.5f, gx2) - fmaxf(acx - aw*0.5f, gx1);
            float h = fminf(acy + ah*0.5f, gy2) - fmaxf(acy - ah*0.5f, gy1);
            float ai = fmaxf(w, 0.0f)*fmaxf(h, 0.0f);
            float un = aw*ah + garea - ai;
            if (ai*bun > bai*un){ bai = ai; bun = un; aidx = r; }
        }
        bool dof = valid && (aidx == anchor_mask[0] || aidx == anchor_mask[1] || aidx == anchor_mask[2]);
        int a3 = aidx % 3;
        float mw = masked_anchors[2*a3], mh = masked_anchors[2*a3+1];
        s_gbox[tid] = make_float4(gx1, gy1, gx2, gy2);
        s_ga[tid] = garea;
        s_dd[tid] = make_float4(gx - xg, gy - yg, gw/mw, gh/mh);
        s_scale[tid] = sqrtf(2.0f - gw*gh/(float)WW/(float)HH);
        if (dof && a3 == a){
            int ci = cell - base;
            if (ci >= 0 && ci < TPB){
                atomicMax(&s_win[ci], tid);                       // last-m-wins (scan overwrite)
                atomicOr(&s_cm[ci][cls >> 5], 1u << (cls & 31));  // OR of one-hots
            }
        }
    }
    __syncthreads();

    // ---- phase B: per-cell loss ----
    double l = 0.0, lc = 0.0;
    bool pos = false;
    const int hw = base + tid;
    if (hw < HW && no > 0){
        int xg = hw % WW, yg = hw / WW;
        size_t obase = ((size_t)(b*CH + a*(5+NUM_CLASSES)))*HW + hw;
        float o0 = outputs[obase];
        float o1 = outputs[obase + HW];
        float o2 = outputs[obase + 2*HW];
        float o3 = outputs[obase + 3*HW];
        float o4 = outputs[obase + 4*HW];
        float px = sigmoidf_(o0) + (float)xg;
        float py = sigmoidf_(o1) + (float)yg;
        float e2 = expf(o2), e3 = expf(o3);
        float pw = e2*masked_anchors[2*a], ph = e3*masked_anchors[2*a+1];
        float px1 = px - pw*0.5f, py1 = py - ph*0.5f;
        float px2 = px + pw*0.5f, py2 = py + ph*0.5f;
        float pc = 0.7f*pw*ph;
        // boolean max loop: sign(maxdiff) == sign(max_iou - 0.7) by cross-mult
        float md = -1.0f;
        for (int m = 0; m < no; ++m){
            float4 gb = s_gbox[m];
            float ga = s_ga[m];
            float w = fminf(px2, gb.z) - fmaxf(px1, gb.x);
            float h = fminf(py2, gb.w) - fmaxf(py1, gb.y);
            float ai = fmaxf(w, 0.0f)*fmaxf(h, 0.0f);
            float thr = fmaf(0.7f, ga, pc);          // 0.7*(parea+garea)
            md = fmaxf(md, fmaf(1.7f, ai, -thr));    // 1.7*ai - thr
        }
        pos = (md > 0.0f);
        int win = s_win[tid];
        float sp4 = softplus_(o4);
        if (win >= 0){
            // exact max_iou needed only here (~800 cells): short refinement loop
            float bax = 0.0f, bun = 1.0f;
            float parea = pw*ph;
            for (int m = 0; m < no; ++m){
                float4 gb = s_gbox[m];
                float w = fminf(px2, gb.z) - fmaxf(px1, gb.x);
                float h = fminf(py2, gb.w) - fmaxf(py1, gb.y);
                float ai = fmaxf(w, 0.0f)*fmaxf(h, 0.0f);
                float un = parea + s_ga[m] - ai;
                if (ai*bun > bax*un){ bax = ai; bun = un; }
            }
            float mi = bax/bun;                      // one fdiv, winner cells only
            l += (double)(sp4 - mi*o4);              // bce(sigma(o4), mi)
            float4 dd = s_dd[win];
            float s = s_scale[win];
            float w2 = s*s;
            l += (double)((softplus_(o0) - dd.x*o0)*w2);
            l += (double)((softplus_(o1) - dd.y*o1)*w2);
            float d2 = e2*s - dd.z*s, d3 = e3*s - dd.w*s;
            l += 0.5*((double)(d2*d2) + (double)(d3*d3));
            unsigned int c0 = s_cm[tid][0], c1 = s_cm[tid][1], c2 = s_cm[tid][2];
            #pragma unroll 8
            for (int c = 0; c < NUM_CLASSES; ++c){
                float oc = outputs[obase + (size_t)(5+c)*HW];
                unsigned int w = (c < 32) ? c0 : ((c < 64) ? c1 : c2);
                float tt = ((w >> (c & 31)) & 1u) ? 1.0f : 0.0f;
                l += (double)(softplus_(oc) - tt*oc);
            }
        } else {
            if (md >= 0.0f) lc += (double)sp4;       // kept only if npos[b]==0
            else            l  += (double)sp4;
        }
    }

    // ---- block reduce (shuffle tree within wave, 8 wave partials) ----
    for (int off = 32; off > 0; off >>= 1){
        l  += __shfl_down(l,  off);
        lc += __shfl_down(lc, off);
    }
    unsigned long long pbal = __ballot(pos);
    int wid = tid >> 6;
    if ((tid & 63) == 0){
        s_rl[wid] = l; s_rlc[wid] = lc; s_anyw[wid] = (pbal != 0ull) ? 1 : 0;
    }
    __syncthreads();
    if (tid == 0){
        double bl = 0.0, blc = 0.0; int anyp = 0;
        for (int i = 0; i < 8; ++i){ bl += s_rl[i]; blc += s_rlc[i]; anyp |= s_anyw[i]; }
        // relaxed device-scope RMWs, striped across lines -> no hot-line queue
        atomicAdd(&acc_l[(bid & 15)*16], bl);
        if (blc != 0.0) atomicAdd(&acc_lc[b*16], blc);
        if (anyp) atomicOr(&posfl[b*32], 1);
        __builtin_amdgcn_s_waitcnt(0);   // data RMWs ack'd at coherence point
        int prev = -1;
        unsigned int cp = atomicAdd(&colcnt[ba*32], 1u);
        if (cp == (unsigned int)(BX - 1)){
            // column complete -> global ticket (only 48 blocks ever touch cnt)
            unsigned int v = __hip_atomic_load(cnt, __ATOMIC_RELAXED,
                                              __HIP_MEMORY_SCOPE_AGENT);
            if (v >= (unsigned int)NBA) atomicCAS(cnt, v, 0u);   // poison clean
            prev = (int)atomicAdd(cnt, 1u);
        }
        s_prev = prev;
    }
    __syncthreads();

    // ---- final block (last column-winner): reduce + self-clean all state ----
    if (s_prev == NBA - 1){
        if (tid < 16)      s_fa[tid]      = atomicExchD(&acc_l[tid*16], 0.0);
        else if (tid < 32) s_fc[tid - 16] = atomicExchD(&acc_lc[(tid-16)*16], 0.0);
        else if (tid < 48) s_fp[tid - 32] = atomicExch(&posfl[(tid-32)*32], 0);
        else if (tid < 96) atomicExch(&colcnt[(tid-48)*32], 0u);
        __syncthreads();
        if (tid == 0){
            double t = 0.0;
            for (int i = 0; i < 16; ++i) t += s_fa[i];
            for (int bb = 0; bb < BB; ++bb) if (!s_fp[bb]) t += s_fc[bb];
            out[0] = (float)t;
            atomicExch(cnt, 0u);         // global ticket clean for next call
        }
    }
}

extern "C" void kernel_launch(void* const* d_in, const int* in_sizes, int n_in,
                              void* d_out, int out_size, void* d_ws, size_t ws_size,
                              hipStream_t stream) {
    const float* outputs        = (const float*)d_in[0];
    const float* targets        = (const float*)d_in[1];
    const float* masked_anchors = (const float*)d_in[2];
    const float* ref_anchors    = (const float*)d_in[3];
    const int*   anchor_mask    = (const int*)d_in[4];

    dim3 grid(BX, NBA);
    k_all<<<grid, TPB, 0, stream>>>(outputs, targets, masked_anchors, ref_anchors,
                                    anchor_mask, (char*)d_ws, (float*)d_out);
}

// Round 8
// 21.857 us; speedup vs baseline: 1.2453x; 1.2453x over previous
//
#include <hip/hip_runtime.h>
#include <math.h>

#define NUM_CLASSES 80
#define BB 16
#define AA 3
#define HH 85
#define WW 85
#define HW (HH*WW)
#define MM 50
#define CH (AA*(5+NUM_CLASSES))   // 255
#define TPB 256
#define BX ((HW + TPB - 1)/TPB)   // 29 hw-windows per (b,a)
#define NBA (BB*AA)               // 48 columns
#define NBLK (BX*NBA)             // 1392 blocks

__device__ __forceinline__ float sigmoidf_(float x){ return 1.0f/(1.0f+expf(-x)); }
// bce(sigmoid(x),t) == softplus(x) - t*x (exact; no saturation for |x| < ~16)
__device__ __forceinline__ float softplus_(float x){
    return fmaxf(x, 0.0f) + log1pf(expf(-fabsf(x)));
}
__device__ __forceinline__ double atomicExchD(double* p, double v){
    unsigned long long old = atomicExch((unsigned long long*)p, __double_as_longlong(v));
    return __longlong_as_double(old);
}

// ws layout (128B-line separated):
//   acc_l [16 lines]  @ 0      : striped f64 loss partials (relaxed atomicAdd)
//   acc_lc[16 lines]  @ 2048   : per-batch conditional-conf partials
//   posfl [16 lines]  @ 4096   : per-batch any-positive flags
//   colcnt[48 lines]  @ 6144   : per-ba column tickets (29 blocks each)
//   cnt   [1]         @ 12288  : global ticket (48 column-winners only)
__global__ void __launch_bounds__(TPB) k_all(
        const float* __restrict__ outputs,
        const float* __restrict__ targets,
        const float* __restrict__ masked_anchors,
        const float* __restrict__ ref_anchors,
        const int* __restrict__ anchor_mask,
        char* __restrict__ wsb,
        float* __restrict__ out)
{
    double* acc_l  = (double*)(wsb);
    double* acc_lc = (double*)(wsb + 2048);
    int*    posfl  = (int*)(wsb + 4096);
    unsigned int* colcnt = (unsigned int*)(wsb + 6144);
    unsigned int* cnt    = (unsigned int*)(wsb + 12288);

    __shared__ float4 s_gbox[MM];        // (gx1, gy1, gx2, gy2)
    __shared__ float  s_ga[MM];          // garea
    __shared__ float4 s_dd[MM];          // delta (dx, dy, dw, dh)
    __shared__ float  s_scale[MM];
    __shared__ int    s_no;
    __shared__ int    s_win[TPB];
    __shared__ unsigned int s_cm[TPB][3];
    __shared__ double s_rl[4], s_rlc[4];
    __shared__ int    s_anyw[4];
    __shared__ int    s_prev;
    __shared__ double s_fa[16], s_fc[16];
    __shared__ int    s_fp[16];

    const int tid  = threadIdx.x;
    const int ba   = blockIdx.y;           // b*AA + a (column id)
    const int b    = ba / AA, a = ba % AA;
    const int base = blockIdx.x * TPB;
    const int bid  = ba * BX + blockIdx.x;

    // Clean poisoned column ticket. At check time this block hasn't incremented,
    // so live values are <= BX-1 = 28; CAS on v>=BX can never hit live state.
    if (tid == 0){
        unsigned int v = __hip_atomic_load(&colcnt[ba*32], __ATOMIC_RELAXED,
                                           __HIP_MEMORY_SCOPE_AGENT);
        if (v >= (unsigned int)BX) atomicCAS(&colcnt[ba*32], v, 0u);
    }

    s_win[tid] = -1;
    s_cm[tid][0] = 0u; s_cm[tid][1] = 0u; s_cm[tid][2] = 0u;

    // ---- phase A: per-GT metadata for batch b (threads 0..MM-1, wave 0) ----
    float g0=0.f,g1=0.f,g2=0.f,g3=0.f,g4=0.f;
    bool gflag = false;
    if (tid < MM){
        const float* g = targets + ((size_t)b*MM + tid)*5;
        g0=g[0]; g1=g[1]; g2=g[2]; g3=g[3]; g4=g[4];
        gflag = (g0+g1+g2+g3+g4) > 0.0f;
    }
    unsigned long long bal = __ballot(gflag);
    if (tid == 0) s_no = __popcll(bal);
    __syncthreads();
    const int no = s_no;

    if (tid < MM){
        float gx = g0*(float)WW, gy = g1*(float)HH, gw = g2*(float)WW, gh = g3*(float)HH;
        int cls = min(max((int)g4, 0), NUM_CLASSES-1);
        bool valid = (tid < no);
        int cx = (int)floorf(gx), cy = (int)floorf(gy);
        int cell = min(max(cy*WW + cx, 0), HW-1);
        float xg = (float)(cell % WW), yg = (float)(cell / WW);
        float gx1 = gx - gw*0.5f, gy1 = gy - gh*0.5f;
        float gx2 = gx + gw*0.5f, gy2 = gy + gh*0.5f;
        float garea = gw*gh;
        // 9-anchor argmax via cross-multiplication (first-max-wins, like jnp.argmax)
        float bai = -1.0f, bun = 1.0f; int aidx = 0;
        for (int r = 0; r < 9; ++r){
            float off = (r % 3 == 0) ? 0.5f : 0.0f;  // ref_grid.at[:, 0::3, :2].add(0.5)
            float acx = xg + off, acy = yg + off;
            float aw = ref_anchors[2*r], ah = ref_anchors[2*r+1];
            float w = fminf(acx + aw*0.5f, gx2) - fmaxf(acx - aw*0.5f, gx1);
            float h = fminf(acy + ah*0.5f, gy2) - fmaxf(acy - ah*0.5f, gy1);
            float ai = fmaxf(w, 0.0f)*fmaxf(h, 0.0f);
            float un = aw*ah + garea - ai;
            if (ai*bun > bai*un){ bai = ai; bun = un; aidx = r; }
        }
        bool dof = valid && (aidx == anchor_mask[0] || aidx == anchor_mask[1] || aidx == anchor_mask[2]);
        int a3 = aidx % 3;
        float mw = masked_anchors[2*a3], mh = masked_anchors[2*a3+1];
        s_gbox[tid] = make_float4(gx1, gy1, gx2, gy2);
        s_ga[tid] = garea;
        s_dd[tid] = make_float4(gx - xg, gy - yg, gw/mw, gh/mh);
        s_scale[tid] = sqrtf(2.0f - gw*gh/(float)WW/(float)HH);
        if (dof && a3 == a){
            int ci = cell - base;
            if (ci >= 0 && ci < TPB){
                atomicMax(&s_win[ci], tid);                       // last-m-wins (scan overwrite)
                atomicOr(&s_cm[ci][cls >> 5], 1u << (cls & 31));  // OR of one-hots
            }
        }
    }
    __syncthreads();

    // ---- phase B: per-cell loss ----
    double l = 0.0, lc = 0.0;
    bool pos = false;
    const int hw = base + tid;
    if (hw < HW && no > 0){
        int xg = hw % WW, yg = hw / WW;
        size_t obase = ((size_t)(b*CH + a*(5+NUM_CLASSES)))*HW + hw;
        float o0 = outputs[obase];
        float o1 = outputs[obase + HW];
        float o2 = outputs[obase + 2*HW];
        float o3 = outputs[obase + 3*HW];
        float o4 = outputs[obase + 4*HW];
        float px = sigmoidf_(o0) + (float)xg;
        float py = sigmoidf_(o1) + (float)yg;
        float e2 = expf(o2), e3 = expf(o3);
        float pw = e2*masked_anchors[2*a], ph = e3*masked_anchors[2*a+1];
        float px1 = px - pw*0.5f, py1 = py - ph*0.5f;
        float px2 = px + pw*0.5f, py2 = py + ph*0.5f;
        float pc = 0.7f*pw*ph;
        // boolean max loop: sign(maxdiff) == sign(max_iou - 0.7) by cross-mult
        float md = -1.0f;
        for (int m = 0; m < no; ++m){
            float4 gb = s_gbox[m];
            float ga = s_ga[m];
            float w = fminf(px2, gb.z) - fmaxf(px1, gb.x);
            float h = fminf(py2, gb.w) - fmaxf(py1, gb.y);
            float ai = fmaxf(w, 0.0f)*fmaxf(h, 0.0f);
            float thr = fmaf(0.7f, ga, pc);          // 0.7*(parea+garea)
            md = fmaxf(md, fmaf(1.7f, ai, -thr));    // 1.7*ai - thr
        }
        pos = (md > 0.0f);
        int win = s_win[tid];
        float sp4 = softplus_(o4);
        if (win >= 0){
            // exact max_iou needed only here (~800 cells): short refinement loop
            float bax = 0.0f, bun = 1.0f;
            float parea = pw*ph;
            for (int m = 0; m < no; ++m){
                float4 gb = s_gbox[m];
                float w = fminf(px2, gb.z) - fmaxf(px1, gb.x);
                float h = fminf(py2, gb.w) - fmaxf(py1, gb.y);
                float ai = fmaxf(w, 0.0f)*fmaxf(h, 0.0f);
                float un = parea + s_ga[m] - ai;
                if (ai*bun > bax*un){ bax = ai; bun = un; }
            }
            float mi = bax/bun;                      // one fdiv, winner cells only
            l += (double)(sp4 - mi*o4);              // bce(sigma(o4), mi)
            float4 dd = s_dd[win];
            float s = s_scale[win];
            float w2 = s*s;
            l += (double)((softplus_(o0) - dd.x*o0)*w2);
            l += (double)((softplus_(o1) - dd.y*o1)*w2);
            float d2 = e2*s - dd.z*s, d3 = e3*s - dd.w*s;
            l += 0.5*((double)(d2*d2) + (double)(d3*d3));
            unsigned int c0 = s_cm[tid][0], c1 = s_cm[tid][1], c2 = s_cm[tid][2];
            #pragma unroll 8
            for (int c = 0; c < NUM_CLASSES; ++c){
                float oc = outputs[obase + (size_t)(5+c)*HW];
                unsigned int w = (c < 32) ? c0 : ((c < 64) ? c1 : c2);
                float tt = ((w >> (c & 31)) & 1u) ? 1.0f : 0.0f;
                l += (double)(softplus_(oc) - tt*oc);
            }
        } else {
            if (md >= 0.0f) lc += (double)sp4;       // kept only if npos[b]==0
            else            l  += (double)sp4;
        }
    }

    // ---- block reduce (shuffle tree within wave, 4 wave partials) ----
    for (int off = 32; off > 0; off >>= 1){
        l  += __shfl_down(l,  off);
        lc += __shfl_down(lc, off);
    }
    unsigned long long pbal = __ballot(pos);
    int wid = tid >> 6;
    if ((tid & 63) == 0){
        s_rl[wid] = l; s_rlc[wid] = lc; s_anyw[wid] = (pbal != 0ull) ? 1 : 0;
    }
    __syncthreads();
    if (tid == 0){
        double bl  = s_rl[0] + s_rl[1] + s_rl[2] + s_rl[3];
        double blc = s_rlc[0] + s_rlc[1] + s_rlc[2] + s_rlc[3];
        int anyp = s_anyw[0] | s_anyw[1] | s_anyw[2] | s_anyw[3];
        // relaxed device-scope RMWs, striped across lines -> no hot-line queue
        atomicAdd(&acc_l[(bid & 15)*16], bl);
        if (blc != 0.0) atomicAdd(&acc_lc[b*16], blc);
        if (anyp) atomicOr(&posfl[b*32], 1);
        __builtin_amdgcn_s_waitcnt(0);   // data RMWs ack'd at coherence point
        int prev = -1;
        unsigned int cp = atomicAdd(&colcnt[ba*32], 1u);
        if (cp == (unsigned int)(BX - 1)){
            // column complete -> global ticket (only 48 blocks ever touch cnt)
            unsigned int v = __hip_atomic_load(cnt, __ATOMIC_RELAXED,
                                              __HIP_MEMORY_SCOPE_AGENT);
            if (v >= (unsigned int)NBA) atomicCAS(cnt, v, 0u);   // poison clean
            prev = (int)atomicAdd(cnt, 1u);
        }
        s_prev = prev;
    }
    __syncthreads();

    // ---- final block (last column-winner): reduce + self-clean all state ----
    if (s_prev == NBA - 1){
        if (tid < 16)      s_fa[tid]      = atomicExchD(&acc_l[tid*16], 0.0);
        else if (tid < 32) s_fc[tid - 16] = atomicExchD(&acc_lc[(tid-16)*16], 0.0);
        else if (tid < 48) s_fp[tid - 32] = atomicExch(&posfl[(tid-32)*32], 0);
        else if (tid < 96) atomicExch(&colcnt[(tid-48)*32], 0u);
        __syncthreads();
        if (tid == 0){
            double t = 0.0;
            for (int i = 0; i < 16; ++i) t += s_fa[i];
            for (int bb = 0; bb < BB; ++bb) if (!s_fp[bb]) t += s_fc[bb];
            out[0] = (float)t;
            atomicExch(cnt, 0u);         // global ticket clean for next call
        }
    }
}

extern "C" void kernel_launch(void* const* d_in, const int* in_sizes, int n_in,
                              void* d_out, int out_size, void* d_ws, size_t ws_size,
                              hipStream_t stream) {
    const float* outputs        = (const float*)d_in[0];
    const float* targets        = (const float*)d_in[1];
    const float* masked_anchors = (const float*)d_in[2];
    const float* ref_anchors    = (const float*)d_in[3];
    const int*   anchor_mask    = (const int*)d_in[4];

    dim3 grid(BX, NBA);
    k_all<<<grid, TPB, 0, stream>>>(outputs, targets, masked_anchors, ref_anchors,
                                    anchor_mask, (char*)d_ws, (float*)d_out);
}

// Round 9
// 19.416 us; speedup vs baseline: 1.4018x; 1.1257x over previous
//
#include <hip/hip_runtime.h>
#include <math.h>

#define NUM_CLASSES 80
#define BB 16
#define AA 3
#define HH 85
#define WW 85
#define HW (HH*WW)
#define MM 50
#define CH (AA*(5+NUM_CLASSES))   // 255
#define TPB 256
#define BX ((HW + TPB - 1)/TPB)   // 29 hw-windows per (b,a)
#define NBA (BB*AA)               // 48 columns
#define NBLK (BX*NBA)             // 1392 blocks
#define LCAP 64                   // winner-list capacity (max 50 GTs/batch)

__device__ __forceinline__ float sigmoidf_(float x){ return 1.0f/(1.0f+expf(-x)); }
// bce(sigmoid(x),t) == softplus(x) - t*x (exact; no saturation for |x| < ~16)
__device__ __forceinline__ float softplus_(float x){
    return fmaxf(x, 0.0f) + log1pf(expf(-fabsf(x)));
}
__device__ __forceinline__ double atomicExchD(double* p, double v){
    unsigned long long old = atomicExch((unsigned long long*)p, __double_as_longlong(v));
    return __longlong_as_double(old);
}

// ws layout (128B-line separated):
//   acc_l [16 lines]  @ 0      : striped f64 loss partials (relaxed atomicAdd)
//   acc_lc[16 lines]  @ 2048   : per-batch conditional-conf partials
//   posfl [16 lines]  @ 4096   : per-batch any-positive flags
//   colcnt[48 lines]  @ 6144   : per-ba column tickets (29 blocks each)
//   cnt   [1]         @ 12288  : global ticket (48 column-winners only)
__global__ void __launch_bounds__(TPB) k_all(
        const float* __restrict__ outputs,
        const float* __restrict__ targets,
        const float* __restrict__ masked_anchors,
        const float* __restrict__ ref_anchors,
        const int* __restrict__ anchor_mask,
        char* __restrict__ wsb,
        float* __restrict__ out)
{
    double* acc_l  = (double*)(wsb);
    double* acc_lc = (double*)(wsb + 2048);
    int*    posfl  = (int*)(wsb + 4096);
    unsigned int* colcnt = (unsigned int*)(wsb + 6144);
    unsigned int* cnt    = (unsigned int*)(wsb + 12288);

    __shared__ float4 s_gbox[MM];        // (gx1, gy1, gx2, gy2)
    __shared__ float  s_ga[MM];          // garea
    __shared__ float4 s_dd[MM];          // delta (dx, dy, dw, dh)
    __shared__ float  s_scale[MM];
    __shared__ int    s_no;
    __shared__ int    s_win[TPB];
    __shared__ unsigned int s_cm[TPB][3];
    __shared__ int    s_nwin;
    __shared__ int4   s_list[LCAP];      // (hw, cm0, cm1, cm2)
    __shared__ double s_rl[4], s_rlc[4];
    __shared__ int    s_anyw[4];
    __shared__ int    s_prev;
    __shared__ double s_fa[16], s_fc[16];
    __shared__ int    s_fp[16];

    const int tid  = threadIdx.x;
    const int ba   = blockIdx.y;           // b*AA + a (column id)
    const int b    = ba / AA, a = ba % AA;
    const int base = blockIdx.x * TPB;
    const int bid  = ba * BX + blockIdx.x;

    // Clean poisoned column ticket. At check time this block hasn't incremented,
    // so live values are <= BX-1 = 28; CAS on v>=BX can never hit live state.
    if (tid == 0){
        unsigned int v = __hip_atomic_load(&colcnt[ba*32], __ATOMIC_RELAXED,
                                           __HIP_MEMORY_SCOPE_AGENT);
        if (v >= (unsigned int)BX) atomicCAS(&colcnt[ba*32], v, 0u);
        s_nwin = 0;
    }

    s_win[tid] = -1;
    s_cm[tid][0] = 0u; s_cm[tid][1] = 0u; s_cm[tid][2] = 0u;

    // ---- phase A: per-GT metadata for batch b (threads 0..MM-1, wave 0) ----
    float g0=0.f,g1=0.f,g2=0.f,g3=0.f,g4=0.f;
    bool gflag = false;
    if (tid < MM){
        const float* g = targets + ((size_t)b*MM + tid)*5;
        g0=g[0]; g1=g[1]; g2=g[2]; g3=g[3]; g4=g[4];
        gflag = (g0+g1+g2+g3+g4) > 0.0f;
    }
    unsigned long long bal = __ballot(gflag);
    if (tid == 0) s_no = __popcll(bal);
    __syncthreads();
    const int no = s_no;

    if (tid < MM){
        float gx = g0*(float)WW, gy = g1*(float)HH, gw = g2*(float)WW, gh = g3*(float)HH;
        int cls = min(max((int)g4, 0), NUM_CLASSES-1);
        bool valid = (tid < no);
        int cx = (int)floorf(gx), cy = (int)floorf(gy);
        int cell = min(max(cy*WW + cx, 0), HW-1);
        float xg = (float)(cell % WW), yg = (float)(cell / WW);
        float gx1 = gx - gw*0.5f, gy1 = gy - gh*0.5f;
        float gx2 = gx + gw*0.5f, gy2 = gy + gh*0.5f;
        float garea = gw*gh;
        // 9-anchor argmax via cross-multiplication (first-max-wins, like jnp.argmax)
        float bai = -1.0f, bun = 1.0f; int aidx = 0;
        for (int r = 0; r < 9; ++r){
            float off = (r % 3 == 0) ? 0.5f : 0.0f;  // ref_grid.at[:, 0::3, :2].add(0.5)
            float acx = xg + off, acy = yg + off;
            float aw = ref_anchors[2*r], ah = ref_anchors[2*r+1];
            float w = fminf(acx + aw*0.5f, gx2) - fmaxf(acx - aw*0.5f, gx1);
            float h = fminf(acy + ah*0.5f, gy2) - fmaxf(acy - ah*0.5f, gy1);
            float ai = fmaxf(w, 0.0f)*fmaxf(h, 0.0f);
            float un = aw*ah + garea - ai;
            if (ai*bun > bai*un){ bai = ai; bun = un; aidx = r; }
        }
        bool dof = valid && (aidx == anchor_mask[0] || aidx == anchor_mask[1] || aidx == anchor_mask[2]);
        int a3 = aidx % 3;
        float mw = masked_anchors[2*a3], mh = masked_anchors[2*a3+1];
        s_gbox[tid] = make_float4(gx1, gy1, gx2, gy2);
        s_ga[tid] = garea;
        s_dd[tid] = make_float4(gx - xg, gy - yg, gw/mw, gh/mh);
        s_scale[tid] = sqrtf(2.0f - gw*gh/(float)WW/(float)HH);
        if (dof && a3 == a){
            int ci = cell - base;
            if (ci >= 0 && ci < TPB){
                atomicMax(&s_win[ci], tid);                       // last-m-wins (scan overwrite)
                atomicOr(&s_cm[ci][cls >> 5], 1u << (cls & 31));  // OR of one-hots
            }
        }
    }
    __syncthreads();

    // ---- phase B: per-cell loss (conf + box at owning thread; class deferred) ----
    double l = 0.0, lc = 0.0;
    bool pos = false;
    const int hw = base + tid;
    const size_t cbase = ((size_t)(b*CH + a*(5+NUM_CLASSES)))*HW;
    if (hw < HW && no > 0){
        int xg = hw % WW, yg = hw / WW;
        size_t obase = cbase + hw;
        float o0 = outputs[obase];
        float o1 = outputs[obase + HW];
        float o2 = outputs[obase + 2*HW];
        float o3 = outputs[obase + 3*HW];
        float o4 = outputs[obase + 4*HW];
        float px = sigmoidf_(o0) + (float)xg;
        float py = sigmoidf_(o1) + (float)yg;
        float e2 = expf(o2), e3 = expf(o3);
        float pw = e2*masked_anchors[2*a], ph = e3*masked_anchors[2*a+1];
        float px1 = px - pw*0.5f, py1 = py - ph*0.5f;
        float px2 = px + pw*0.5f, py2 = py + ph*0.5f;
        float pc = 0.7f*pw*ph;
        // boolean max loop: sign(maxdiff) == sign(max_iou - 0.7) by cross-mult
        float md = -1.0f;
        for (int m = 0; m < no; ++m){
            float4 gb = s_gbox[m];
            float ga = s_ga[m];
            float w = fminf(px2, gb.z) - fmaxf(px1, gb.x);
            float h = fminf(py2, gb.w) - fmaxf(py1, gb.y);
            float ai = fmaxf(w, 0.0f)*fmaxf(h, 0.0f);
            float thr = fmaf(0.7f, ga, pc);          // 0.7*(parea+garea)
            md = fmaxf(md, fmaf(1.7f, ai, -thr));    // 1.7*ai - thr
        }
        pos = (md > 0.0f);
        int win = s_win[tid];
        float sp4 = softplus_(o4);
        if (win >= 0){
            // exact max_iou needed only here (~800 cells): short refinement loop
            float bax = 0.0f, bun = 1.0f;
            float parea = pw*ph;
            for (int m = 0; m < no; ++m){
                float4 gb = s_gbox[m];
                float w = fminf(px2, gb.z) - fmaxf(px1, gb.x);
                float h = fminf(py2, gb.w) - fmaxf(py1, gb.y);
                float ai = fmaxf(w, 0.0f)*fmaxf(h, 0.0f);
                float un = parea + s_ga[m] - ai;
                if (ai*bun > bax*un){ bax = ai; bun = un; }
            }
            float mi = bax/bun;                      // one fdiv, winner cells only
            l += (double)(sp4 - mi*o4);              // bce(sigma(o4), mi)
            float4 dd = s_dd[win];
            float s = s_scale[win];
            float w2 = s*s;
            l += (double)((softplus_(o0) - dd.x*o0)*w2);
            l += (double)((softplus_(o1) - dd.y*o1)*w2);
            float d2 = e2*s - dd.z*s, d3 = e3*s - dd.w*s;
            l += 0.5*((double)(d2*d2) + (double)(d3*d3));
            // defer class BCE: push (hw, classmask) for block-parallel processing
            int idx = atomicAdd(&s_nwin, 1);
            s_list[idx] = make_int4(hw, (int)s_cm[tid][0], (int)s_cm[tid][1],
                                    (int)s_cm[tid][2]);
        } else {
            if (md >= 0.0f) lc += (double)sp4;       // kept only if npos[b]==0
            else            l  += (double)sp4;
        }
    }
    __syncthreads();

    // ---- class BCE, block-parallel: 3 entries x 80 classes per pass ----
    // Each entry's 80 strided loads issue in ONE latency round (80 lanes),
    // replacing the per-winner-thread serial 80-load chain (straggler tail).
    const int nw = s_nwin;
    const int e_off = tid / 80;          // 0..2 for tid<240
    const int c     = tid - e_off*80;    // class id 0..79
    for (int e0 = 0; e0 < nw; e0 += 3){
        int e = e0 + e_off;
        if (tid < 240 && e < nw){
            int4 ent = s_list[e];
            float oc = outputs[cbase + ent.x + (size_t)(5+c)*HW];
            unsigned int w = (c < 32) ? (unsigned int)ent.y
                           : (c < 64) ? (unsigned int)ent.z : (unsigned int)ent.w;
            float tt = ((w >> (c & 31)) & 1u) ? 1.0f : 0.0f;
            l += (double)(softplus_(oc) - tt*oc);
        }
    }

    // ---- block reduce (shuffle tree within wave, 4 wave partials) ----
    for (int off = 32; off > 0; off >>= 1){
        l  += __shfl_down(l,  off);
        lc += __shfl_down(lc, off);
    }
    unsigned long long pbal = __ballot(pos);
    int wid = tid >> 6;
    if ((tid & 63) == 0){
        s_rl[wid] = l; s_rlc[wid] = lc; s_anyw[wid] = (pbal != 0ull) ? 1 : 0;
    }
    __syncthreads();
    if (tid == 0){
        double bl  = s_rl[0] + s_rl[1] + s_rl[2] + s_rl[3];
        double blc = s_rlc[0] + s_rlc[1] + s_rlc[2] + s_rlc[3];
        int anyp = s_anyw[0] | s_anyw[1] | s_anyw[2] | s_anyw[3];
        // relaxed device-scope RMWs, striped across lines -> no hot-line queue
        atomicAdd(&acc_l[(bid & 15)*16], bl);
        if (blc != 0.0) atomicAdd(&acc_lc[b*16], blc);
        if (anyp) atomicOr(&posfl[b*32], 1);
        __builtin_amdgcn_s_waitcnt(0);   // data RMWs ack'd at coherence point
        int prev = -1;
        unsigned int cp = atomicAdd(&colcnt[ba*32], 1u);
        if (cp == (unsigned int)(BX - 1)){
            // column complete -> global ticket (only 48 blocks ever touch cnt)
            unsigned int v = __hip_atomic_load(cnt, __ATOMIC_RELAXED,
                                              __HIP_MEMORY_SCOPE_AGENT);
            if (v >= (unsigned int)NBA) atomicCAS(cnt, v, 0u);   // poison clean
            prev = (int)atomicAdd(cnt, 1u);
        }
        s_prev = prev;
    }
    __syncthreads();

    // ---- final block (last column-winner): reduce + self-clean all state ----
    if (s_prev == NBA - 1){
        if (tid < 16)      s_fa[tid]      = atomicExchD(&acc_l[tid*16], 0.0);
        else if (tid < 32) s_fc[tid - 16] = atomicExchD(&acc_lc[(tid-16)*16], 0.0);
        else if (tid < 48) s_fp[tid - 32] = atomicExch(&posfl[(tid-32)*32], 0);
        else if (tid < 96) atomicExch(&colcnt[(tid-48)*32], 0u);
        __syncthreads();
        if (tid == 0){
            double t = 0.0;
            for (int i = 0; i < 16; ++i) t += s_fa[i];
            for (int bb = 0; bb < BB; ++bb) if (!s_fp[bb]) t += s_fc[bb];
            out[0] = (float)t;
            atomicExch(cnt, 0u);         // global ticket clean for next call
        }
    }
}

extern "C" void kernel_launch(void* const* d_in, const int* in_sizes, int n_in,
                              void* d_out, int out_size, void* d_ws, size_t ws_size,
                              hipStream_t stream) {
    const float* outputs        = (const float*)d_in[0];
    const float* targets        = (const float*)d_in[1];
    const float* masked_anchors = (const float*)d_in[2];
    const float* ref_anchors    = (const float*)d_in[3];
    const int*   anchor_mask    = (const int*)d_in[4];

    dim3 grid(BX, NBA);
    k_all<<<grid, TPB, 0, stream>>>(outputs, targets, masked_anchors, ref_anchors,
                                    anchor_mask, (char*)d_ws, (float*)d_out);
}

// Round 10
// 18.817 us; speedup vs baseline: 1.4465x; 1.0318x over previous
//
#include <hip/hip_runtime.h>
#include <math.h>

#define NUM_CLASSES 80
#define BB 16
#define AA 3
#define HH 85
#define WW 85
#define HW (HH*WW)
#define MM 50
#define CH (AA*(5+NUM_CLASSES))   // 255
#define TPB 256
#define BX ((HW + TPB - 1)/TPB)   // 29 hw-windows per (b,a)
#define NBA (BB*AA)               // 48 columns
#define NBLK (BX*NBA)             // 1392 blocks
#define LCAP 64                   // winner-list capacity (max 50 GTs/batch)

__device__ __forceinline__ float sigmoidf_(float x){ return 1.0f/(1.0f+expf(-x)); }
// bce(sigmoid(x),t) == softplus(x) - t*x (exact; no saturation for |x| < ~16)
__device__ __forceinline__ float softplus_(float x){
    return fmaxf(x, 0.0f) + log1pf(expf(-fabsf(x)));
}
__device__ __forceinline__ double atomicExchD(double* p, double v){
    unsigned long long old = atomicExch((unsigned long long*)p, __double_as_longlong(v));
    return __longlong_as_double(old);
}

// ws layout (128B-line separated):
//   acc_l [16 lines]  @ 0      : striped f64 loss partials (relaxed atomicAdd)
//   acc_lc[16 lines]  @ 2048   : per-batch conditional-conf partials
//   posfl [16 lines]  @ 4096   : per-batch any-positive flags
//   colcnt[48 lines]  @ 6144   : per-ba column tickets (29 blocks each)
//   cnt   [1]         @ 12288  : global ticket (48 column-winners only)
__global__ void __launch_bounds__(TPB) k_all(
        const float* __restrict__ outputs,
        const float* __restrict__ targets,
        const float* __restrict__ masked_anchors,
        const float* __restrict__ ref_anchors,
        const int* __restrict__ anchor_mask,
        char* __restrict__ wsb,
        float* __restrict__ out)
{
    double* acc_l  = (double*)(wsb);
    double* acc_lc = (double*)(wsb + 2048);
    int*    posfl  = (int*)(wsb + 4096);
    unsigned int* colcnt = (unsigned int*)(wsb + 6144);
    unsigned int* cnt    = (unsigned int*)(wsb + 12288);

    __shared__ float4 s_gbox[MM];        // (gx1, gy1, gx2, gy2)
    __shared__ float  s_ga[MM];          // garea
    __shared__ float4 s_dd[MM];          // delta (dx, dy, dw, dh)
    __shared__ float  s_scale[MM];
    __shared__ int    s_no;
    __shared__ int    s_win[TPB];
    __shared__ unsigned int s_cm[TPB][3];
    __shared__ int    s_nwin;
    __shared__ int4   s_list[LCAP];      // (hw, cm0, cm1, cm2)
    __shared__ double s_rl[4], s_rlc[4];
    __shared__ int    s_anyw[4];
    __shared__ int    s_prev;
    __shared__ double s_fa[16], s_fc[16];
    __shared__ int    s_fp[16];

    const int tid  = threadIdx.x;
    const int ba   = blockIdx.y;           // b*AA + a (column id)
    const int b    = ba / AA, a = ba % AA;
    const int base = blockIdx.x * TPB;
    const int bid  = ba * BX + blockIdx.x;

    // ---- EARLY LOADS: issue ALL global reads first; latency hides under ----
    // ---- ticket-clean + phase A (first use is after the barrier).       ----
    const int hw = base + tid;
    const bool act = (hw < HW);
    const size_t cbase = ((size_t)(b*CH + a*(5+NUM_CLASSES)))*HW;
    const size_t obase = cbase + hw;
    float o0=0.f,o1=0.f,o2=0.f,o3=0.f,o4=0.f;
    if (act){
        o0 = outputs[obase];
        o1 = outputs[obase + HW];
        o2 = outputs[obase + 2*HW];
        o3 = outputs[obase + 3*HW];
        o4 = outputs[obase + 4*HW];
    }
    float maw = masked_anchors[2*a], mah = masked_anchors[2*a+1];
    float g0=0.f,g1=0.f,g2=0.f,g3=0.f,g4=0.f;
    if (tid < MM){
        const float* g = targets + ((size_t)b*MM + tid)*5;
        g0=g[0]; g1=g[1]; g2=g[2]; g3=g[3]; g4=g[4];
    }

    // Clean poisoned column ticket. At check time this block hasn't incremented,
    // so live values are <= BX-1 = 28; CAS on v>=BX can never hit live state.
    if (tid == 0){
        unsigned int v = __hip_atomic_load(&colcnt[ba*32], __ATOMIC_RELAXED,
                                           __HIP_MEMORY_SCOPE_AGENT);
        if (v >= (unsigned int)BX) atomicCAS(&colcnt[ba*32], v, 0u);
        s_nwin = 0;
    }

    s_win[tid] = -1;
    s_cm[tid][0] = 0u; s_cm[tid][1] = 0u; s_cm[tid][2] = 0u;

    // ---- phase A: per-GT metadata for batch b (threads 0..MM-1, wave 0) ----
    bool gflag = (tid < MM) && ((g0+g1+g2+g3+g4) > 0.0f);
    unsigned long long bal = __ballot(gflag);
    if (tid == 0) s_no = __popcll(bal);
    __syncthreads();
    const int no = s_no;

    if (tid < MM){
        float gx = g0*(float)WW, gy = g1*(float)HH, gw = g2*(float)WW, gh = g3*(float)HH;
        int cls = min(max((int)g4, 0), NUM_CLASSES-1);
        bool valid = (tid < no);
        int cx = (int)floorf(gx), cy = (int)floorf(gy);
        int cell = min(max(cy*WW + cx, 0), HW-1);
        float xg = (float)(cell % WW), yg = (float)(cell / WW);
        float gx1 = gx - gw*0.5f, gy1 = gy - gh*0.5f;
        float gx2 = gx + gw*0.5f, gy2 = gy + gh*0.5f;
        float garea = gw*gh;
        // 9-anchor argmax via cross-multiplication (first-max-wins, like jnp.argmax)
        float bai = -1.0f, bun = 1.0f; int aidx = 0;
        for (int r = 0; r < 9; ++r){
            float off = (r % 3 == 0) ? 0.5f : 0.0f;  // ref_grid.at[:, 0::3, :2].add(0.5)
            float acx = xg + off, acy = yg + off;
            float aw = ref_anchors[2*r], ah = ref_anchors[2*r+1];
            float w = fminf(acx + aw*0.5f, gx2) - fmaxf(acx - aw*0.5f, gx1);
            float h = fminf(acy + ah*0.5f, gy2) - fmaxf(acy - ah*0.5f, gy1);
            float ai = fmaxf(w, 0.0f)*fmaxf(h, 0.0f);
            float un = aw*ah + garea - ai;
            if (ai*bun > bai*un){ bai = ai; bun = un; aidx = r; }
        }
        bool dof = valid && (aidx == anchor_mask[0] || aidx == anchor_mask[1] || aidx == anchor_mask[2]);
        int a3 = aidx % 3;
        float mw = masked_anchors[2*a3], mh = masked_anchors[2*a3+1];
        s_gbox[tid] = make_float4(gx1, gy1, gx2, gy2);
        s_ga[tid] = garea;
        s_dd[tid] = make_float4(gx - xg, gy - yg, gw/mw, gh/mh);
        s_scale[tid] = sqrtf(2.0f - gw*gh/(float)WW/(float)HH);
        if (dof && a3 == a){
            int ci = cell - base;
            if (ci >= 0 && ci < TPB){
                atomicMax(&s_win[ci], tid);                       // last-m-wins (scan overwrite)
                atomicOr(&s_cm[ci][cls >> 5], 1u << (cls & 31));  // OR of one-hots
            }
        }
    }
    __syncthreads();

    // ---- phase B: per-cell loss (conf + box at owning thread; class deferred) ----
    double l = 0.0, lc = 0.0;
    bool pos = false;
    if (act && no > 0){
        int xg = hw % WW, yg = hw / WW;
        float px = sigmoidf_(o0) + (float)xg;
        float py = sigmoidf_(o1) + (float)yg;
        float e2 = expf(o2), e3 = expf(o3);
        float pw = e2*maw, ph = e3*mah;
        float px1 = px - pw*0.5f, py1 = py - ph*0.5f;
        float px2 = px + pw*0.5f, py2 = py + ph*0.5f;
        float pc = 0.7f*pw*ph;
        // boolean max loop: sign(maxdiff) == sign(max_iou - 0.7) by cross-mult
        float md = -1.0f;
        for (int m = 0; m < no; ++m){
            float4 gb = s_gbox[m];
            float ga = s_ga[m];
            float w = fminf(px2, gb.z) - fmaxf(px1, gb.x);
            float h = fminf(py2, gb.w) - fmaxf(py1, gb.y);
            float ai = fmaxf(w, 0.0f)*fmaxf(h, 0.0f);
            float thr = fmaf(0.7f, ga, pc);          // 0.7*(parea+garea)
            md = fmaxf(md, fmaf(1.7f, ai, -thr));    // 1.7*ai - thr
        }
        pos = (md > 0.0f);
        int win = s_win[tid];
        float sp4 = softplus_(o4);
        if (win >= 0){
            // exact max_iou needed only here (~800 cells): short refinement loop
            float bax = 0.0f, bun = 1.0f;
            float parea = pw*ph;
            for (int m = 0; m < no; ++m){
                float4 gb = s_gbox[m];
                float w = fminf(px2, gb.z) - fmaxf(px1, gb.x);
                float h = fminf(py2, gb.w) - fmaxf(py1, gb.y);
                float ai = fmaxf(w, 0.0f)*fmaxf(h, 0.0f);
                float un = parea + s_ga[m] - ai;
                if (ai*bun > bax*un){ bax = ai; bun = un; }
            }
            float mi = bax/bun;                      // one fdiv, winner cells only
            l += (double)(sp4 - mi*o4);              // bce(sigma(o4), mi)
            float4 dd = s_dd[win];
            float s = s_scale[win];
            float w2 = s*s;
            l += (double)((softplus_(o0) - dd.x*o0)*w2);
            l += (double)((softplus_(o1) - dd.y*o1)*w2);
            float d2 = e2*s - dd.z*s, d3 = e3*s - dd.w*s;
            l += 0.5*((double)(d2*d2) + (double)(d3*d3));
            // defer class BCE: push (hw, classmask) for block-parallel processing
            int idx = atomicAdd(&s_nwin, 1);
            s_list[idx] = make_int4(hw, (int)s_cm[tid][0], (int)s_cm[tid][1],
                                    (int)s_cm[tid][2]);
        } else {
            if (md >= 0.0f) lc += (double)sp4;       // kept only if npos[b]==0
            else            l  += (double)sp4;
        }
    }
    __syncthreads();

    // ---- class BCE, block-parallel: 3 entries x 80 classes per pass ----
    // Each entry's 80 strided loads issue in ONE latency round (80 lanes),
    // replacing the per-winner-thread serial 80-load chain (straggler tail).
    const int nw = s_nwin;
    const int e_off = tid / 80;          // 0..2 for tid<240
    const int c     = tid - e_off*80;    // class id 0..79
    for (int e0 = 0; e0 < nw; e0 += 3){
        int e = e0 + e_off;
        if (tid < 240 && e < nw){
            int4 ent = s_list[e];
            float oc = outputs[cbase + ent.x + (size_t)(5+c)*HW];
            unsigned int w = (c < 32) ? (unsigned int)ent.y
                           : (c < 64) ? (unsigned int)ent.z : (unsigned int)ent.w;
            float tt = ((w >> (c & 31)) & 1u) ? 1.0f : 0.0f;
            l += (double)(softplus_(oc) - tt*oc);
        }
    }

    // ---- block reduce (shuffle tree within wave, 4 wave partials) ----
    for (int off = 32; off > 0; off >>= 1){
        l  += __shfl_down(l,  off);
        lc += __shfl_down(lc, off);
    }
    unsigned long long pbal = __ballot(pos);
    int wid = tid >> 6;
    if ((tid & 63) == 0){
        s_rl[wid] = l; s_rlc[wid] = lc; s_anyw[wid] = (pbal != 0ull) ? 1 : 0;
    }
    __syncthreads();
    if (tid == 0){
        double bl  = s_rl[0] + s_rl[1] + s_rl[2] + s_rl[3];
        double blc = s_rlc[0] + s_rlc[1] + s_rlc[2] + s_rlc[3];
        int anyp = s_anyw[0] | s_anyw[1] | s_anyw[2] | s_anyw[3];
        // relaxed device-scope RMWs, striped across lines -> no hot-line queue
        atomicAdd(&acc_l[(bid & 15)*16], bl);
        if (blc != 0.0) atomicAdd(&acc_lc[b*16], blc);
        if (anyp) atomicOr(&posfl[b*32], 1);
        __builtin_amdgcn_s_waitcnt(0);   // data RMWs ack'd at coherence point
        int prev = -1;
        unsigned int cp = atomicAdd(&colcnt[ba*32], 1u);
        if (cp == (unsigned int)(BX - 1)){
            // column complete -> global ticket (only 48 blocks ever touch cnt)
            unsigned int v = __hip_atomic_load(cnt, __ATOMIC_RELAXED,
                                              __HIP_MEMORY_SCOPE_AGENT);
            if (v >= (unsigned int)NBA) atomicCAS(cnt, v, 0u);   // poison clean
            prev = (int)atomicAdd(cnt, 1u);
        }
        s_prev = prev;
    }
    __syncthreads();

    // ---- final block (last column-winner): reduce + self-clean all state ----
    if (s_prev == NBA - 1){
        if (tid < 16)      s_fa[tid]      = atomicExchD(&acc_l[tid*16], 0.0);
        else if (tid < 32) s_fc[tid - 16] = atomicExchD(&acc_lc[(tid-16)*16], 0.0);
        else if (tid < 48) s_fp[tid - 32] = atomicExch(&posfl[(tid-32)*32], 0);
        else if (tid < 96) atomicExch(&colcnt[(tid-48)*32], 0u);
        __syncthreads();
        if (tid == 0){
            double t = 0.0;
            for (int i = 0; i < 16; ++i) t += s_fa[i];
            for (int bb = 0; bb < BB; ++bb) if (!s_fp[bb]) t += s_fc[bb];
            out[0] = (float)t;
            atomicExch(cnt, 0u);         // global ticket clean for next call
        }
    }
}

extern "C" void kernel_launch(void* const* d_in, const int* in_sizes, int n_in,
                              void* d_out, int out_size, void* d_ws, size_t ws_size,
                              hipStream_t stream) {
    const float* outputs        = (const float*)d_in[0];
    const float* targets        = (const float*)d_in[1];
    const float* masked_anchors = (const float*)d_in[2];
    const float* ref_anchors    = (const float*)d_in[3];
    const int*   anchor_mask    = (const int*)d_in[4];

    dim3 grid(BX, NBA);
    k_all<<<grid, TPB, 0, stream>>>(outputs, targets, masked_anchors, ref_anchors,
                                    anchor_mask, (char*)d_ws, (float*)d_out);
}